// Round 1
// baseline (209.574 us; speedup 1.0000x reference)
//
#include <hip/hip_runtime.h>

typedef __attribute__((ext_vector_type(2))) float f32x2;
typedef __attribute__((ext_vector_type(4))) float f32x4;
typedef __attribute__((ext_vector_type(8))) short s16x8;
typedef __attribute__((ext_vector_type(2))) unsigned int u32x2;
typedef __attribute__((ext_vector_type(4))) unsigned int u32x4;

#define BN 4
#define TN 4096
#define CN 120
#define HN 64

// RNE float->bf16 (finite inputs only)
__device__ __forceinline__ unsigned short f2bf(float f) {
  unsigned int u = __float_as_uint(f);
  unsigned int r = (u + 0x7fffu + ((u >> 16) & 1u)) >> 16;
  return (unsigned short)r;
}

__device__ __forceinline__ float fast_exp2(float x) {
#if __has_builtin(__builtin_amdgcn_exp2f)
  return __builtin_amdgcn_exp2f(x);
#else
  return exp2f(x);
#endif
}

// ---------------------------------------------------------------------------
// Kernel 1: projections. Each block handles 64 rows (one batch's contiguous
// t-range). Computes k,q,v in fp32, writes bf16:
//   Kg [b*T+t][64]  rows
//   Qg [b*T+t][64]  rows, pre-scaled by log2(e)/sqrt(C) (folds softmax scale
//                   AND exp->exp2 conversion into Q)
//   Vt [b][h][t]    transposed so attention's PV A-operand reads are
//                   contiguous 16B rows
// ---------------------------------------------------------------------------
__global__ __launch_bounds__(256) void proj_kernel(
    const float* __restrict__ x, const float* __restrict__ Wk,
    const float* __restrict__ Wq, const float* __restrict__ Wv,
    unsigned short* __restrict__ Kg, unsigned short* __restrict__ Qg,
    unsigned short* __restrict__ Vt) {
  __shared__ union {
    float xl[64 * CN];            // 30720 B
    unsigned short vt[64 * 72];   // 9216 B (pad 72 to dodge bank conflicts)
  } sm;
  const int tid = threadIdx.x;
  const int row0 = blockIdx.x * 64;
  {
    const f32x4* xs = (const f32x4*)(x + (size_t)row0 * CN);
    f32x4* xd = (f32x4*)sm.xl;
    for (int i = tid; i < 64 * CN / 4; i += 256) xd[i] = xs[i];
  }
  __syncthreads();
  const int hp = tid & 31;  // h pair: h = 2hp, 2hp+1
  const int rg = tid >> 5;  // row group: rows rg*8 .. rg*8+7
  f32x2 aK[8], aQ[8], aV[8];
#pragma unroll
  for (int r = 0; r < 8; ++r) { aK[r] = 0.f; aQ[r] = 0.f; aV[r] = 0.f; }
  for (int c = 0; c < CN; c += 4) {
    f32x4 xv[8];
#pragma unroll
    for (int r = 0; r < 8; ++r)
      xv[r] = *(const f32x4*)&sm.xl[(rg * 8 + r) * CN + c];
#pragma unroll
    for (int cc = 0; cc < 4; ++cc) {
      const f32x2 wk = *(const f32x2*)&Wk[(c + cc) * HN + 2 * hp];
      const f32x2 wq = *(const f32x2*)&Wq[(c + cc) * HN + 2 * hp];
      const f32x2 wv = *(const f32x2*)&Wv[(c + cc) * HN + 2 * hp];
#pragma unroll
      for (int r = 0; r < 8; ++r) {
        const float xx = xv[r][cc];
        aK[r] += wk * xx;
        aQ[r] += wq * xx;
        aV[r] += wv * xx;
      }
    }
  }
  const float QSC = 0.131720936f;  // log2(e)/sqrt(120)
#pragma unroll
  for (int r = 0; r < 8; ++r) {
    const int row = rg * 8 + r;
    const size_t idx = (size_t)(row0 + row) * HN + 2 * hp;
    const unsigned int kp =
        (unsigned int)f2bf(aK[r][0]) | ((unsigned int)f2bf(aK[r][1]) << 16);
    const unsigned int qp = (unsigned int)f2bf(aQ[r][0] * QSC) |
                            ((unsigned int)f2bf(aQ[r][1] * QSC) << 16);
    *(unsigned int*)&Kg[idx] = kp;
    *(unsigned int*)&Qg[idx] = qp;
  }
  // V transpose through LDS, then coalesced global write of Vt rows
  __syncthreads();
#pragma unroll
  for (int r = 0; r < 8; ++r) {
    const int row = rg * 8 + r;
    sm.vt[(2 * hp) * 72 + row] = f2bf(aV[r][0]);
    sm.vt[(2 * hp + 1) * 72 + row] = f2bf(aV[r][1]);
  }
  __syncthreads();
  const int h = tid >> 2, ck = tid & 3;
  const int b = row0 >> 12, key0 = row0 & (TN - 1);
  unsigned short* vrow = Vt + (size_t)(b * HN + h) * TN + key0 + ck * 16;
  const u32x4 d0 = *(const u32x4*)&sm.vt[h * 72 + ck * 16];
  const u32x4 d1 = *(const u32x4*)&sm.vt[h * 72 + ck * 16 + 8];
  *(u32x4*)vrow = d0;
  *(u32x4*)(vrow + 8) = d1;
}

// ---------------------------------------------------------------------------
// Kernel 2: attention. One block = 16 queries; 4 waves each own a disjoint
// 1024-key range (no online max: logits bounded, exp2 never overflows, so
// partials (O,l) merge by plain summation at the end).
// Per 64-key step per wave:
//   S^T[key][q] = K-tile * Q^T  (mfma 16x16x32 bf16, frags loaded straight
//                                from global/L2 — every load = 16 full lines)
//   p = exp2(s) truncated to bf16; l += truncated p (bias cancels in P*V/l)
//   P^T through wave-private LDS (144B-padded rows) into B-operand layout
//   O^T[h][q] += Vt-tile * P^T
// ---------------------------------------------------------------------------
__global__ __launch_bounds__(256, 4) void attn_kernel(
    const unsigned short* __restrict__ Qg, const unsigned short* __restrict__ Kg,
    const unsigned short* __restrict__ Vt, float* __restrict__ out) {
  __shared__ union {
    unsigned short p[4][16][72];                  // 9216 B, wave-private rows
    struct { float ob[4][64][17]; float lb[4][16]; } m;  // epilogue merge
  } sm;
  const int bid = blockIdx.x;
  const int xslot = bid & 7;                 // XCD-aware swizzle:
  const int b = xslot >> 1;                  // batch pinned to an XCD pair so
  const int qt = (bid >> 3) | ((xslot & 1) << 7);  // K+Vt (1MB) stays L2-hot
  const int qbase = qt * 16;
  const int tid = threadIdx.x;
  const int wave = tid >> 6, lane = tid & 63;
  const int l15 = lane & 15, quad = lane >> 4;

  // Q B-operand frags: B[k=h][n=q]: q = lane&15, h = quad*8+j (+32)
  const unsigned short* qrow =
      Qg + (size_t)(b * TN + qbase + l15) * HN + quad * 8;
  const s16x8 qf0 = *(const s16x8*)qrow;
  const s16x8 qf1 = *(const s16x8*)(qrow + 32);

  const unsigned short* Kb = Kg + (size_t)b * TN * HN;
  const unsigned short* Vb = Vt + (size_t)b * HN * TN;
  char* const pw = (char*)&sm.p[wave][0][0] + l15 * 144;  // write row q=l15
  char* const pr = (char*)&sm.p[wave][0][0] + l15 * 144 + quad * 16;

  f32x4 o[4];
#pragma unroll
  for (int t = 0; t < 4; ++t) o[t] = 0.f;
  float lacc = 0.f;

  const int kend = wave * 1024 + 1024;
  for (int kb = wave * 1024; kb < kend; kb += 64) {
    f32x4 s[4];
#pragma unroll
    for (int t = 0; t < 4; ++t) s[t] = 0.f;
#pragma unroll
    for (int t = 0; t < 4; ++t) {
      // A-operand: A[m=key16][k=h]: key row = kb+16t+l15, h = quad*8+j
      const unsigned short* kr =
          Kb + (size_t)(kb + t * 16 + l15) * HN + quad * 8;
      const s16x8 a0 = *(const s16x8*)kr;
      const s16x8 a1 = *(const s16x8*)(kr + 32);
      s[t] = __builtin_amdgcn_mfma_f32_16x16x32_bf16(a0, qf0, s[t], 0, 0, 0);
      s[t] = __builtin_amdgcn_mfma_f32_16x16x32_bf16(a1, qf1, s[t], 0, 0, 0);
    }
    // exp2, truncate to bf16, accumulate l from the *truncated* values,
    // store P^T rows: S^T C/D layout: q=l15(col), key = 16t + quad*4 + reg
#pragma unroll
    for (int t = 0; t < 4; ++t) {
      unsigned int u0 = __float_as_uint(fast_exp2(fminf(s[t][0], 80.f)));
      unsigned int u1 = __float_as_uint(fast_exp2(fminf(s[t][1], 80.f)));
      unsigned int u2 = __float_as_uint(fast_exp2(fminf(s[t][2], 80.f)));
      unsigned int u3 = __float_as_uint(fast_exp2(fminf(s[t][3], 80.f)));
      u0 &= 0xffff0000u; u1 &= 0xffff0000u;
      u2 &= 0xffff0000u; u3 &= 0xffff0000u;
      lacc += (__uint_as_float(u0) + __uint_as_float(u1)) +
              (__uint_as_float(u2) + __uint_as_float(u3));
      u32x2 w;
      w.x = (u0 >> 16) | u1;
      w.y = (u2 >> 16) | u3;
      *(u32x2*)(pw + t * 32 + quad * 8) = w;  // keys 16t+quad*4 .. +3
    }
    // O^T += Vt * P^T   (same-wave LDS RAW: DS ops complete in order)
#pragma unroll
    for (int kc = 0; kc < 2; ++kc) {
      // B-operand: B[k=key][n=q]: row q=l15, key bytes quad*16 + kc*64
      const s16x8 pb = *(const s16x8*)(pr + kc * 64);
#pragma unroll
      for (int ht = 0; ht < 4; ++ht) {
        // A-operand: A[m=h16][k=key]: Vt row h=16ht+l15, key = kb+32kc+quad*8+j
        const unsigned short* vr =
            Vb + (size_t)(ht * 16 + l15) * TN + kb + kc * 32 + quad * 8;
        const s16x8 va = *(const s16x8*)vr;
        o[ht] = __builtin_amdgcn_mfma_f32_16x16x32_bf16(va, pb, o[ht], 0, 0, 0);
      }
    }
  }
  // l currently partial per lane (its own keys); reduce across quads
  lacc += __shfl_xor(lacc, 16, 64);
  lacc += __shfl_xor(lacc, 32, 64);
  __syncthreads();  // all waves done with sm.p before union reuse
  if (lane < 16) sm.m.lb[wave][l15] = lacc;
#pragma unroll
  for (int ht = 0; ht < 4; ++ht)
#pragma unroll
    for (int r = 0; r < 4; ++r)
      sm.m.ob[wave][ht * 16 + quad * 4 + r][l15] = o[ht][r];
  __syncthreads();
  // merge 4 key-split partials, normalize, coalesced store
  const int h = tid & 63;
#pragma unroll
  for (int i = 0; i < 4; ++i) {
    const int qq = (i << 2) | (tid >> 6);
    const float ssum = sm.m.ob[0][h][qq] + sm.m.ob[1][h][qq] +
                       sm.m.ob[2][h][qq] + sm.m.ob[3][h][qq];
    const float ll = sm.m.lb[0][qq] + sm.m.lb[1][qq] +
                     sm.m.lb[2][qq] + sm.m.lb[3][qq];
    out[(size_t)(b * TN + qbase + qq) * HN + h] = ssum / ll;
  }
}

extern "C" void kernel_launch(void* const* d_in, const int* in_sizes, int n_in,
                              void* d_out, int out_size, void* d_ws,
                              size_t ws_size, hipStream_t stream) {
  const float* x = (const float*)d_in[0];
  const float* Wk = (const float*)d_in[1];
  const float* Wq = (const float*)d_in[2];
  const float* Wv = (const float*)d_in[3];
  unsigned short* Kg = (unsigned short*)d_ws;             // [B*T][64] bf16
  unsigned short* Qg = Kg + (size_t)BN * TN * HN;         // [B*T][64] bf16
  unsigned short* Vt = Qg + (size_t)BN * TN * HN;         // [B][64][T] bf16
  float* out = (float*)d_out;
  proj_kernel<<<BN * TN / 64, 256, 0, stream>>>(x, Wk, Wq, Wv, Kg, Qg, Vt);
  attn_kernel<<<BN * TN / 16, 256, 0, stream>>>(Qg, Kg, Vt, out);
}